// Round 4
// baseline (476.440 us; speedup 1.0000x reference)
//
#include <hip/hip_runtime.h>
#include <hip/hip_bf16.h>

#define EPS 1e-3f

typedef __attribute__((ext_vector_type(8))) short short8;
typedef __attribute__((ext_vector_type(4))) float v4f;

__device__ __forceinline__ unsigned short f2bf(float f) {
    unsigned int u = __float_as_uint(f);
    unsigned int r = (u + 0x7fffu + ((u >> 16) & 1u)) >> 16;
    return (unsigned short)r;
}

// ---------------------------------------------------------------------------
// Prep: fold biases + BN into per-channel affine; transpose pw_kernel into
// bf16 MFMA B-fragment layout.  (unchanged)
// ---------------------------------------------------------------------------
__global__ __launch_bounds__(256) void prep_kernel(
    const float* __restrict__ dwb,
    const float* __restrict__ g1, const float* __restrict__ b1,
    const float* __restrict__ m1, const float* __restrict__ v1,
    const float* __restrict__ pw, const float* __restrict__ pwb,
    const float* __restrict__ g2, const float* __restrict__ b2,
    const float* __restrict__ m2, const float* __restrict__ v2,
    float* __restrict__ scale1, float* __restrict__ shift1,
    float* __restrict__ s2, float* __restrict__ t2,
    unsigned short* __restrict__ Wt)
{
    int tid = threadIdx.x;
    if (blockIdx.x == 0) {
        if (tid < 64) {
            float inv = g1[tid] * rsqrtf(v1[tid] + EPS);
            scale1[tid] = inv;
            shift1[tid] = dwb[tid] * inv + b1[tid] - m1[tid] * inv;
        }
        if (tid < 128) {
            float inv = g2[tid] * rsqrtf(v2[tid] + EPS);
            s2[tid] = inv;
            t2[tid] = pwb[tid] * inv + b2[tid] - m2[tid] * inv;
        }
    }
    int idx = blockIdx.x * 256 + tid;      // 0..8191
    int j     = idx & 7;
    int lane  = (idx >> 3) & 63;
    int kstep = (idx >> 9) & 1;
    int ntile = idx >> 10;                 // 0..7
    int k = kstep * 32 + (lane >> 4) * 8 + j;
    int f = ntile * 16 + (lane & 15);
    Wt[idx] = f2bf(pw[k * 128 + f]);
}

// ---------------------------------------------------------------------------
// Fused, multi-d sliding-window, T14 register-prefetch version.
// Block: 256 thr, hw-tile = 4(h) x 16(w), DPB=6 consecutive output-d slices.
// Streams 8 slabs (d0-1 .. d0+6) through one LDS buffer; each slab feeds up
// to 3 rotating conv accumulators.  Next slab's global loads are issued
// BEFORE conv of the current slab (T14): HBM latency hides under conv+GEMM.
// B-fragments (pw weights) live in 64 VGPRs for the whole block.
// Grid = 576 blocks -> all co-resident at 3 blocks/CU (LDS 46.6 KB), no tail.
// ---------------------------------------------------------------------------
__global__ __launch_bounds__(256, 3) void fused_kernel(
    const float* __restrict__ x,
    const float* __restrict__ wgt,          // (3,3,3,1,64)
    const float* __restrict__ scale1,
    const float* __restrict__ shift1,
    const unsigned short* __restrict__ Wt,  // bf16 B-fragments (16 KB)
    const float* __restrict__ s2,
    const float* __restrict__ t2,
    float* __restrict__ out)
{
    __shared__ float wS[27 * 64];
    __shared__ float sS[64];
    __shared__ float tS[64];
    __shared__ float s2S[128];
    __shared__ float t2S[128];
    __shared__ float xS[6 * 18 * 66];       // 28512 B, w-stride 66 floats
    __shared__ unsigned short yS[64 * 72];  // 64 rows x 64 ch, +8 short pad

    int tid = threadIdx.x;
    for (int i = tid; i < 27 * 64; i += 256) wS[i] = wgt[i];
    if (tid < 64) { sS[tid] = scale1[tid]; tS[tid] = shift1[tid]; }
    if (tid < 128) { s2S[tid] = s2[tid]; t2S[tid] = t2[tid]; }

    // XCD-aware decode: 576 blocks = 8 xcd * 2 (b,dgrp) * 36 hw
    int n   = blockIdx.x;
    int xcd = n & 7;
    int j   = n >> 3;              // 0..71
    int bdg = xcd * 2 + j / 36;    // 0..15  (b*8 + dgrp)
    int hw  = j % 36;
    int b    = bdg >> 3;
    int dgrp = bdg & 7;
    int d0   = dgrp * 6;
    int w0  = (hw % 3) * 16;
    int h0  = (hw / 3) * 4;

    int tx = tid & 15;            // channel group
    int ty = tid >> 4;            // 0..15
    int c0 = tx * 4;
    int wq = ty & 3;
    int rh = ty >> 2;             // == wave id -> h is wave-uniform

    int wv   = tid >> 6;
    int lane = tid & 63;
    int lrow = lane & 15;
    int quad = lane >> 4;

    // ---- one-time staging coordinate precompute (7 slots/thread) ----
    int  g_off[7], l_off[7];
    bool ldm[7], wrm[7];
    #pragma unroll
    for (int i = 0; i < 7; ++i) {
        int idx = i * 256 + tid;
        bool active = idx < 1728;          // 6h * 18w * 16cg
        int cg  = idx & 15;
        int hwl = idx >> 4;                // 0..107
        int hh  = hwl / 18;
        int ww  = hwl - hh * 18;
        int zh  = h0 + hh - 1;
        int zw  = w0 + ww - 1;
        bool inb = active && zh >= 0 && zh < 48 && zw >= 0 && zw < 48;
        g_off[i] = (zh * 48 + zw) * 64 + cg * 4;
        l_off[i] = (hh * 18 + ww) * 66 + cg * 4;
        ldm[i] = inb;
        wrm[i] = active;
    }

    const long slab_stride = 48 * 48 * 64;
    const float* xbase = x + (long)b * 48 * slab_stride;

    // ---- prologue: prefetch slab k=0 (s = d0-1) into registers ----
    float4 R[7];
    {
        int s = d0 - 1;
        if (s >= 0) {
            const float* xs = xbase + (long)s * slab_stride;
            #pragma unroll
            for (int i = 0; i < 7; ++i)
                if (ldm[i]) R[i] = *(const float4*)(xs + g_off[i]);
        }
    }
    // ---- prologue: B-fragments into registers (16 x short8 = 64 VGPR) ----
    short8 bf[16];
    #pragma unroll
    for (int nn = 0; nn < 16; ++nn)
        bf[nn] = *(const short8*)(Wt + (nn * 64 + lane) * 8);

    __syncthreads();   // wS/sS ready; also gates first xS write

    // 3 rotating accumulator sets
    float4 acc[3][4];
    #pragma unroll
    for (int a = 0; a < 3; ++a)
        #pragma unroll
        for (int r = 0; r < 4; ++r) acc[a][r] = make_float4(0.f, 0.f, 0.f, 0.f);

    #pragma unroll
    for (int k = 0; k < 8; ++k) {
        int s = d0 - 1 + k;                    // slab depth
        bool s_ok = (s >= 0) && (s < 48);      // block-uniform

        // ---- A: write prefetched slab into xS ----
        if (s_ok) {
            #pragma unroll
            for (int i = 0; i < 7; ++i)
                if (wrm[i])
                    *(float4*)(&xS[l_off[i]]) =
                        ldm[i] ? R[i] : make_float4(0.f, 0.f, 0.f, 0.f);
        }

        // ---- B: issue prefetch for slab k+1 (in flight across conv+GEMM) ----
        if (k < 7) {
            int sn = s + 1;
            if (sn >= 0 && sn < 48) {
                const float* xs = xbase + (long)sn * slab_stride;
                #pragma unroll
                for (int i = 0; i < 7; ++i)
                    if (ldm[i]) R[i] = *(const float4*)(xs + g_off[i]);
            }
        }

        __syncthreads();   // xS ready

        // ---- conv: 18 shared ds_reads feed up to 3 output accumulators ----
        if (s_ok) {
            #pragma unroll
            for (int hh = 0; hh < 3; ++hh) {
                const float* rp = &xS[((rh + hh) * 18 + wq * 4) * 66 + c0];
                float4 xv[6];
                #pragma unroll
                for (int p = 0; p < 6; ++p)
                    xv[p] = *(const float4*)(rp + p * 66);
                #pragma unroll
                for (int m = 0; m < 6; ++m) {
                    if (m >= k - 2 && m <= k) {      // folds at compile time
                        const int wz  = k - m;       // weight z-tap
                        const int aid = m % 3;
                        #pragma unroll
                        for (int ww = 0; ww < 3; ++ww) {
                            const float4 wvv = *(const float4*)(&wS[((wz * 3 + hh) * 3 + ww) * 64 + c0]);
                            #pragma unroll
                            for (int r = 0; r < 4; ++r) {
                                acc[aid][r].x += xv[r + ww].x * wvv.x;
                                acc[aid][r].y += xv[r + ww].y * wvv.y;
                                acc[aid][r].z += xv[r + ww].z * wvv.z;
                                acc[aid][r].w += xv[r + ww].w * wvv.w;
                            }
                        }
                    }
                }
            }
        }

        // ---- BN1 + ReLU + bf16 -> yS for output m = k-2 ----
        if (k >= 2) {
            const int aid = (k - 2) % 3;
            float4 s1 = *(const float4*)(&sS[c0]);
            float4 t1 = *(const float4*)(&tS[c0]);
            #pragma unroll
            for (int r = 0; r < 4; ++r) {
                ushort4 o;
                o.x = f2bf(fmaxf(acc[aid][r].x * s1.x + t1.x, 0.f));
                o.y = f2bf(fmaxf(acc[aid][r].y * s1.y + t1.y, 0.f));
                o.z = f2bf(fmaxf(acc[aid][r].z * s1.z + t1.z, 0.f));
                o.w = f2bf(fmaxf(acc[aid][r].w * s1.w + t1.w, 0.f));
                *(ushort4*)(&yS[(ty * 4 + r) * 72 + c0]) = o;
                acc[aid][r] = make_float4(0.f, 0.f, 0.f, 0.f);  // recycle
            }
        }

        __syncthreads();   // yS ready AND conv(k) reads of xS complete

        // ---- GEMM + BN2 + store for output m = k-2 ----
        if (k >= 2) {
            const int m = k - 2;
            const short8 a0 = *(const short8*)(&yS[(wv * 16 + lrow) * 72 + quad * 8]);
            const short8 a1 = *(const short8*)(&yS[(wv * 16 + lrow) * 72 + 32 + quad * 8]);

            v4f g[8];
            #pragma unroll
            for (int nn = 0; nn < 8; ++nn) g[nn] = (v4f){0.f, 0.f, 0.f, 0.f};

            #pragma unroll
            for (int nn = 0; nn < 8; ++nn) {
                g[nn] = __builtin_amdgcn_mfma_f32_16x16x32_bf16(a0, bf[nn * 2 + 0], g[nn], 0, 0, 0);
                g[nn] = __builtin_amdgcn_mfma_f32_16x16x32_bf16(a1, bf[nn * 2 + 1], g[nn], 0, 0, 0);
            }

            int d = d0 + m;
            long base_out = ((((long)b * 48 + d) * 48 + (h0 + wv)) * 48 + w0) * 128;
            #pragma unroll
            for (int nn = 0; nn < 8; ++nn) {
                int f = nn * 16 + lrow;
                float sf = s2S[f];
                float tf = t2S[f];
                #pragma unroll
                for (int r = 0; r < 4; ++r) {
                    float v = fmaxf(g[nn][r] * sf + tf, 0.f);
                    out[base_out + (quad * 4 + r) * 128 + f] = v;
                }
            }
        }
    }
}

// ---------------------------------------------------------------------------
extern "C" void kernel_launch(void* const* d_in, const int* in_sizes, int n_in,
                              void* d_out, int out_size, void* d_ws, size_t ws_size,
                              hipStream_t stream)
{
    const float* x   = (const float*)d_in[0];
    const float* dwk = (const float*)d_in[1];
    const float* dwb = (const float*)d_in[2];
    const float* g1  = (const float*)d_in[3];
    const float* b1  = (const float*)d_in[4];
    const float* m1  = (const float*)d_in[5];
    const float* v1  = (const float*)d_in[6];
    const float* pw  = (const float*)d_in[7];
    const float* pwb = (const float*)d_in[8];
    const float* g2  = (const float*)d_in[9];
    const float* b2  = (const float*)d_in[10];
    const float* m2  = (const float*)d_in[11];
    const float* v2  = (const float*)d_in[12];

    float* outp = (float*)d_out;

    float* scale1 = (float*)d_ws;
    float* shift1 = scale1 + 64;
    float* s2     = scale1 + 128;
    float* t2     = scale1 + 256;
    unsigned short* Wt = (unsigned short*)((char*)d_ws + 2048);

    hipLaunchKernelGGL(prep_kernel, dim3(32), dim3(256), 0, stream,
                       dwb, g1, b1, m1, v1, pw, pwb, g2, b2, m2, v2,
                       scale1, shift1, s2, t2, Wt);

    hipLaunchKernelGGL(fused_kernel, dim3(576), dim3(256), 0, stream,
                       x, dwk, scale1, shift1, Wt, s2, t2, outp);
}

// Round 5
// 309.985 us; speedup vs baseline: 1.5370x; 1.5370x over previous
//
#include <hip/hip_runtime.h>
#include <hip/hip_bf16.h>

#define EPS 1e-3f

typedef __attribute__((ext_vector_type(8))) short short8;
typedef __attribute__((ext_vector_type(4))) float v4f;

__device__ __forceinline__ unsigned short f2bf(float f) {
    unsigned int u = __float_as_uint(f);
    unsigned int r = (u + 0x7fffu + ((u >> 16) & 1u)) >> 16;
    return (unsigned short)r;
}

// ---------------------------------------------------------------------------
// Prep: fold biases + BN into per-channel affine; transpose pw_kernel into
// bf16 MFMA B-fragment layout.  (unchanged)
// ---------------------------------------------------------------------------
__global__ __launch_bounds__(256) void prep_kernel(
    const float* __restrict__ dwb,
    const float* __restrict__ g1, const float* __restrict__ b1,
    const float* __restrict__ m1, const float* __restrict__ v1,
    const float* __restrict__ pw, const float* __restrict__ pwb,
    const float* __restrict__ g2, const float* __restrict__ b2,
    const float* __restrict__ m2, const float* __restrict__ v2,
    float* __restrict__ scale1, float* __restrict__ shift1,
    float* __restrict__ s2, float* __restrict__ t2,
    unsigned short* __restrict__ Wt)
{
    int tid = threadIdx.x;
    if (blockIdx.x == 0) {
        if (tid < 64) {
            float inv = g1[tid] * rsqrtf(v1[tid] + EPS);
            scale1[tid] = inv;
            shift1[tid] = dwb[tid] * inv + b1[tid] - m1[tid] * inv;
        }
        if (tid < 128) {
            float inv = g2[tid] * rsqrtf(v2[tid] + EPS);
            s2[tid] = inv;
            t2[tid] = pwb[tid] * inv + b2[tid] - m2[tid] * inv;
        }
    }
    int idx = blockIdx.x * 256 + tid;      // 0..8191
    int j     = idx & 7;
    int lane  = (idx >> 3) & 63;
    int kstep = (idx >> 9) & 1;
    int ntile = idx >> 10;                 // 0..7
    int k = kstep * 32 + (lane >> 4) * 8 + j;
    int f = ntile * 16 + (lane & 15);
    Wt[idx] = f2bf(pw[k * 128 + f]);
}

// ---------------------------------------------------------------------------
// Fused kernel, async-LDS pipeline version.
// Block: 256 thr, hw-tile = 4(h) x 16(w), DPB=8 output-d slices.
// Slabs staged with global_load_lds (direct to LDS, no VGPR round-trip).
// Linear xS layout [6][18][64] with both-sides XOR swizzle:
//   slot' = cg ^ ((ww + (ww>>3)) & 7)   (4 w-quads -> 4 distinct 16B cols)
// applied to the per-lane global SOURCE address and to the conv READ offsets.
// OOB h/w lanes are exec-masked; their slots pre-zeroed once (slab-invariant).
// Pipeline per iter k: [wait vmcnt + s_barrier] conv(k) -> BN1(k-2)->yS ->
// __syncthreads -> issue slab k+1 (flies during GEMM) -> GEMM(k-2)+stores.
// Top wait = vmcnt(32): the 32 newest VMEM ops are our stores; slab loads are
// older and vmcnt retires in order -> loads guaranteed landed.
// Wt lives in LDS so the GEMM never touches vmcnt.  LDS 60.2 KB, 2 blocks/CU
// (matches measured residency).  Grid 432: all blocks co-resident, no tail.
// ---------------------------------------------------------------------------
__global__ __launch_bounds__(256, 2) void fused_kernel(
    const float* __restrict__ x,
    const float* __restrict__ wgt,          // (3,3,3,1,64)
    const float* __restrict__ scale1,
    const float* __restrict__ shift1,
    const unsigned short* __restrict__ Wt,  // bf16 B-fragments (16 KB)
    const float* __restrict__ s2,
    const float* __restrict__ t2,
    float* __restrict__ out)
{
    __shared__ float xS[6 * 18 * 64];        // 27648 B, linear (swizzled slots)
    __shared__ unsigned short wtS[8192];     // 16384 B
    __shared__ unsigned short yS[64 * 72];   // 9216 B
    __shared__ float wS[27 * 64];            // 6912 B
    __shared__ float sS[64];
    __shared__ float tS[64];
    __shared__ float s2S[128];
    __shared__ float t2S[128];

    int tid = threadIdx.x;

    // decode: 432 blocks = 8 xcd * 54;  54 = 1.5 (b,dgrp) groups of 36 hw
    int n   = blockIdx.x;
    int g   = (n & 7) * 54 + (n >> 3);
    int bdg = g / 36;              // 0..11
    int hw  = g % 36;
    int b    = bdg / 6;
    int dgrp = bdg % 6;
    int d0   = dgrp * 8;
    int w0  = (hw % 3) * 16;
    int h0  = (hw / 3) * 4;

    int tx = tid & 15;            // channel group
    int ty = tid >> 4;            // 0..15
    int c0 = tx * 4;
    int wq = ty & 3;
    int rh = ty >> 2;             // == wave id -> h is wave-uniform

    int wv   = tid >> 6;
    int lane = tid & 63;
    int lrow = lane & 15;
    int quad = lane >> 4;

    // ---- conv read offsets (swizzled), constant per thread ----
    int coloff[6];
    #pragma unroll
    for (int p = 0; p < 6; ++p) {
        int ww = wq * 4 + p;
        int f  = (ww + (ww >> 3)) & 7;
        coloff[p] = ww * 64 + ((tx ^ f) << 2);
    }

    // ---- staging coords: wave wv owns chunks wv*7 .. wv*7+6 (27 chunks,
    //      wave3 duplicates chunk 26).  Per chunk: 64 lanes x 16 B linear. ----
    int  goff[7], lb[7];
    bool inb[7];
    #pragma unroll
    for (int i = 0; i < 7; ++i) {
        int c = wv * 7 + i; if (c > 26) c = 26;
        int idx  = c * 64 + lane;          // 0..1727
        int cell = idx >> 4;               // hh*18+ww
        int slot = idx & 15;
        int hh = cell / 18;
        int ww = cell - hh * 18;
        int f  = (ww + (ww >> 3)) & 7;
        int cg = slot ^ f;                 // swizzled source channel-group
        int zh = h0 + hh - 1;
        int zw = w0 + ww - 1;
        inb[i]  = (zh >= 0 && zh < 48 && zw >= 0 && zw < 48);
        goff[i] = (zh * 48 + zw) * 64 + cg * 4;   // float index (may be junk if !inb)
        lb[i]   = c * 256;                        // float index of chunk base
    }

    // pre-zero OOB slots (never written by loads; slab-invariant masks)
    #pragma unroll
    for (int i = 0; i < 7; ++i)
        if (!inb[i])
            *(float4*)(&xS[lb[i] + lane * 4]) = make_float4(0.f, 0.f, 0.f, 0.f);

    const long slab_stride = 48 * 48 * 64;
    const float* xbase = x + (long)b * 48 * slab_stride;

    // ---- issue slab 0 (s = d0-1) ----
    {
        int s0 = d0 - 1;
        if (s0 >= 0) {
            const float* xs = xbase + (long)s0 * slab_stride;
            #pragma unroll
            for (int i = 0; i < 7; ++i)
                if (inb[i])
                    __builtin_amdgcn_global_load_lds(xs + goff[i], &xS[lb[i]], 16, 0, 0);
        }
    }

    // ---- prologue LDS fills (overlap with slab-0 flight) ----
    for (int i = tid; i < 27 * 64; i += 256) wS[i] = wgt[i];
    for (int i = tid; i < 1024; i += 256)
        ((float4*)wtS)[i] = ((const float4*)Wt)[i];
    if (tid < 64) { sS[tid] = scale1[tid]; tS[tid] = shift1[tid]; }
    if (tid < 128) { s2S[tid] = s2[tid]; t2S[tid] = t2[tid]; }

    __syncthreads();   // drains everything incl. slab 0 (once, prologue only)

    // 3 rotating accumulator sets
    float4 acc[3][4];
    #pragma unroll
    for (int a = 0; a < 3; ++a)
        #pragma unroll
        for (int r = 0; r < 4; ++r) acc[a][r] = make_float4(0.f, 0.f, 0.f, 0.f);

    #pragma unroll
    for (int k = 0; k < 10; ++k) {
        // ---- top wait: slab k landed.  k<=2: no stores yet -> vmcnt(0).
        //      k>=3: 32 stores are the newest ops; slab loads older -> 32. ----
        if (k <= 2) asm volatile("s_waitcnt vmcnt(0)" ::: "memory");
        else        asm volatile("s_waitcnt vmcnt(32)" ::: "memory");
        __builtin_amdgcn_s_barrier();
        __builtin_amdgcn_sched_barrier(0);

        int s = d0 - 1 + k;
        bool s_ok = (s >= 0) && (s < 48);      // block-uniform

        // ---- conv: 18 swizzled ds_reads feed up to 3 accumulators ----
        if (s_ok) {
            #pragma unroll
            for (int dh = 0; dh < 3; ++dh) {
                const float* rp = &xS[(rh + dh) * 1152];
                float4 xv[6];
                #pragma unroll
                for (int p = 0; p < 6; ++p)
                    xv[p] = *(const float4*)(rp + coloff[p]);
                #pragma unroll
                for (int m = 0; m < 8; ++m) {
                    if (m >= k - 2 && m <= k) {      // folds at compile time
                        const int wz  = k - m;       // weight z-tap
                        const int aid = m % 3;
                        #pragma unroll
                        for (int ww2 = 0; ww2 < 3; ++ww2) {
                            const float4 wvv = *(const float4*)(&wS[((wz * 3 + dh) * 3 + ww2) * 64 + c0]);
                            #pragma unroll
                            for (int r = 0; r < 4; ++r) {
                                acc[aid][r].x += xv[r + ww2].x * wvv.x;
                                acc[aid][r].y += xv[r + ww2].y * wvv.y;
                                acc[aid][r].z += xv[r + ww2].z * wvv.z;
                                acc[aid][r].w += xv[r + ww2].w * wvv.w;
                            }
                        }
                    }
                }
            }
        }

        // ---- BN1 + ReLU + bf16 -> yS for output m = k-2 ----
        if (k >= 2) {
            const int aid = (k - 2) % 3;
            float4 s1 = *(const float4*)(&sS[c0]);
            float4 t1 = *(const float4*)(&tS[c0]);
            #pragma unroll
            for (int r = 0; r < 4; ++r) {
                ushort4 o;
                o.x = f2bf(fmaxf(acc[aid][r].x * s1.x + t1.x, 0.f));
                o.y = f2bf(fmaxf(acc[aid][r].y * s1.y + t1.y, 0.f));
                o.z = f2bf(fmaxf(acc[aid][r].z * s1.z + t1.z, 0.f));
                o.w = f2bf(fmaxf(acc[aid][r].w * s1.w + t1.w, 0.f));
                *(ushort4*)(&yS[(ty * 4 + r) * 72 + c0]) = o;
                acc[aid][r] = make_float4(0.f, 0.f, 0.f, 0.f);  // recycle
            }
        }

        __syncthreads();   // conv reads of xS done; yS visible

        // ---- issue slab k+1 (flies during GEMM + stores) ----
        if (k <= 8) {
            int sn = d0 + k;
            if (sn < 48) {
                const float* xs = xbase + (long)sn * slab_stride;
                #pragma unroll
                for (int i = 0; i < 7; ++i)
                    if (inb[i])
                        __builtin_amdgcn_global_load_lds(xs + goff[i], &xS[lb[i]], 16, 0, 0);
            }
        }
        __builtin_amdgcn_sched_barrier(0);   // pin: loads issue before stores

        // ---- GEMM + BN2 + store for output m = k-2 (Wt from LDS) ----
        if (k >= 2) {
            const int m = k - 2;
            const short8 a0 = *(const short8*)(&yS[(wv * 16 + lrow) * 72 + quad * 8]);
            const short8 a1 = *(const short8*)(&yS[(wv * 16 + lrow) * 72 + 32 + quad * 8]);

            v4f gacc[8];
            #pragma unroll
            for (int nn = 0; nn < 8; ++nn) gacc[nn] = (v4f){0.f, 0.f, 0.f, 0.f};

            #pragma unroll
            for (int nn = 0; nn < 8; ++nn) {
                short8 b0 = *(const short8*)(&wtS[(nn * 2 + 0) * 512 + lane * 8]);
                short8 b1 = *(const short8*)(&wtS[(nn * 2 + 1) * 512 + lane * 8]);
                gacc[nn] = __builtin_amdgcn_mfma_f32_16x16x32_bf16(a0, b0, gacc[nn], 0, 0, 0);
                gacc[nn] = __builtin_amdgcn_mfma_f32_16x16x32_bf16(a1, b1, gacc[nn], 0, 0, 0);
            }

            int d = d0 + m;
            long base_out = ((((long)b * 48 + d) * 48 + (h0 + wv)) * 48 + w0) * 128;
            #pragma unroll
            for (int nn = 0; nn < 8; ++nn) {
                int f = nn * 16 + lrow;
                float sf = s2S[f];
                float tf = t2S[f];
                #pragma unroll
                for (int r = 0; r < 4; ++r) {
                    float v = fmaxf(gacc[nn][r] * sf + tf, 0.f);
                    out[base_out + (quad * 4 + r) * 128 + f] = v;
                }
            }
        }
    }
}

// ---------------------------------------------------------------------------
extern "C" void kernel_launch(void* const* d_in, const int* in_sizes, int n_in,
                              void* d_out, int out_size, void* d_ws, size_t ws_size,
                              hipStream_t stream)
{
    const float* x   = (const float*)d_in[0];
    const float* dwk = (const float*)d_in[1];
    const float* dwb = (const float*)d_in[2];
    const float* g1  = (const float*)d_in[3];
    const float* b1  = (const float*)d_in[4];
    const float* m1  = (const float*)d_in[5];
    const float* v1  = (const float*)d_in[6];
    const float* pw  = (const float*)d_in[7];
    const float* pwb = (const float*)d_in[8];
    const float* g2  = (const float*)d_in[9];
    const float* b2  = (const float*)d_in[10];
    const float* m2  = (const float*)d_in[11];
    const float* v2  = (const float*)d_in[12];

    float* outp = (float*)d_out;

    float* scale1 = (float*)d_ws;
    float* shift1 = scale1 + 64;
    float* s2     = scale1 + 128;
    float* t2     = scale1 + 256;
    unsigned short* Wt = (unsigned short*)((char*)d_ws + 2048);

    hipLaunchKernelGGL(prep_kernel, dim3(32), dim3(256), 0, stream,
                       dwb, g1, b1, m1, v1, pw, pwb, g2, b2, m2, v2,
                       scale1, shift1, s2, t2, Wt);

    hipLaunchKernelGGL(fused_kernel, dim3(432), dim3(256), 0, stream,
                       x, dwk, scale1, shift1, Wt, s2, t2, outp);
}

// Round 6
// 205.467 us; speedup vs baseline: 2.3188x; 1.5087x over previous
//
#include <hip/hip_runtime.h>
#include <hip/hip_bf16.h>

#define EPS 1e-3f

typedef __attribute__((ext_vector_type(8))) short short8;
typedef __attribute__((ext_vector_type(4))) float v4f;

__device__ __forceinline__ unsigned short f2bf(float f) {
    unsigned int u = __float_as_uint(f);
    unsigned int r = (u + 0x7fffu + ((u >> 16) & 1u)) >> 16;
    return (unsigned short)r;
}

// ---------------------------------------------------------------------------
// Prep: fold biases + BN into per-channel affine; transpose pw_kernel into
// bf16 MFMA B-fragment layout.  (unchanged)
// ---------------------------------------------------------------------------
__global__ __launch_bounds__(256) void prep_kernel(
    const float* __restrict__ dwb,
    const float* __restrict__ g1, const float* __restrict__ b1,
    const float* __restrict__ m1, const float* __restrict__ v1,
    const float* __restrict__ pw, const float* __restrict__ pwb,
    const float* __restrict__ g2, const float* __restrict__ b2,
    const float* __restrict__ m2, const float* __restrict__ v2,
    float* __restrict__ scale1, float* __restrict__ shift1,
    float* __restrict__ s2, float* __restrict__ t2,
    unsigned short* __restrict__ Wt)
{
    int tid = threadIdx.x;
    if (blockIdx.x == 0) {
        if (tid < 64) {
            float inv = g1[tid] * rsqrtf(v1[tid] + EPS);
            scale1[tid] = inv;
            shift1[tid] = dwb[tid] * inv + b1[tid] - m1[tid] * inv;
        }
        if (tid < 128) {
            float inv = g2[tid] * rsqrtf(v2[tid] + EPS);
            s2[tid] = inv;
            t2[tid] = pwb[tid] * inv + b2[tid] - m2[tid] * inv;
        }
    }
    int idx = blockIdx.x * 256 + tid;      // 0..8191
    int j     = idx & 7;
    int lane  = (idx >> 3) & 63;
    int kstep = (idx >> 9) & 1;
    int ntile = idx >> 10;                 // 0..7
    int k = kstep * 32 + (lane >> 4) * 8 + j;
    int f = ntile * 16 + (lane & 15);
    Wt[idx] = f2bf(pw[k * 128 + f]);
}

// ---------------------------------------------------------------------------
// Fused kernel, occupancy-first version.
// Theory: all rounds show VALU busy-time ~13us vs 104+us wall -> 87% idle,
// latency-bound at ~7 waves/CU.  The xS staging LDS (28.5 KB) was the
// occupancy cap, and it only fixed a cache-side amplification that the
// 256 MB L3 absorbs anyway.  So: NO x staging -- conv loads x directly from
// global (clamped addresses + edge masks, private, barrier-free).  Keep
// DPB=6 d-sliding with 3 rotating accumulators (each slab read once per
// block, 18 float4 loads per k-iter).  LDS = yS + weights only (17.7 KB).
// Grid 576 all co-resident at 3 blocks/CU -> ~18 waves/CU hides everything.
// Barriers: 2 per iter (yS WAR/RAW), only for k>=2.
// ---------------------------------------------------------------------------
__global__ __launch_bounds__(256, 3) void fused_kernel(
    const float* __restrict__ x,
    const float* __restrict__ wgt,          // (3,3,3,1,64)
    const float* __restrict__ scale1,
    const float* __restrict__ shift1,
    const unsigned short* __restrict__ Wt,  // bf16 B-fragments (16 KB)
    const float* __restrict__ s2,
    const float* __restrict__ t2,
    float* __restrict__ out)
{
    __shared__ float wS[27 * 64];            // 6912 B
    __shared__ float sS[64];
    __shared__ float tS[64];
    __shared__ float s2S[128];
    __shared__ float t2S[128];
    __shared__ unsigned short yS[64 * 72];   // 9216 B

    int tid = threadIdx.x;
    for (int i = tid; i < 27 * 64; i += 256) wS[i] = wgt[i];
    if (tid < 64) { sS[tid] = scale1[tid]; tS[tid] = shift1[tid]; }
    if (tid < 128) { s2S[tid] = s2[tid]; t2S[tid] = t2[tid]; }
    __syncthreads();

    // XCD-aware decode: 576 blocks = 8 xcd * 72 (bijective)
    int n   = blockIdx.x;
    int g   = (n & 7) * 72 + (n >> 3);   // each XCD owns a contiguous range
    int bdg = g / 36;              // 0..15 = b*8 + dgrp
    int hw  = g % 36;
    int b    = bdg >> 3;
    int dgrp = bdg & 7;
    int d0   = dgrp * 6;
    int w0  = (hw % 3) * 16;
    int h0  = (hw / 3) * 4;

    int tx = tid & 15;            // channel group
    int ty = tid >> 4;            // 0..15
    int c0 = tx * 4;
    int wq = ty & 3;
    int rh = ty >> 2;             // == wave id -> h is wave-uniform

    int wv   = tid >> 6;
    int lane = tid & 63;
    int lrow = lane & 15;
    int quad = lane >> 4;

    // ---- per-thread invariant conv addressing (clamped) ----
    int w0t = w0 + wq * 4;
    float mwL = (w0t >= 1)  ? 1.f : 0.f;   // window p=0 (zw = w0t-1)
    float mwR = (w0t <= 43) ? 1.f : 0.f;   // window p=5 (zw = w0t+4)
    int wcl[6];
    #pragma unroll
    for (int p = 0; p < 6; ++p)
        wcl[p] = min(max(w0t - 1 + p, 0), 47) * 64;

    int h = h0 + rh;
    bool hok[3];
    int  hcl[3];
    #pragma unroll
    for (int hh = 0; hh < 3; ++hh) {
        int zh = h + hh - 1;
        hok[hh] = (zh >= 0 && zh < 48);
        hcl[hh] = min(max(zh, 0), 47) * 48 * 64;
    }

    const long slab_stride = 48 * 48 * 64;

    // 3 rotating accumulator sets (all indices compile-time after unroll)
    float4 acc[3][4];
    #pragma unroll
    for (int a = 0; a < 3; ++a)
        #pragma unroll
        for (int r = 0; r < 4; ++r) acc[a][r] = make_float4(0.f, 0.f, 0.f, 0.f);

    #pragma unroll
    for (int k = 0; k < 8; ++k) {
        int s = d0 - 1 + k;                    // slab depth
        bool s_ok = (s >= 0) && (s < 48);      // block-uniform

        // ---- conv: direct global loads (private, no barriers) ----
        if (s_ok) {
            const float* dp = x + ((long)(b * 48 + s) * 48 * 48) * 64 + c0;
            #pragma unroll
            for (int hh = 0; hh < 3; ++hh) {
                if (hok[hh]) {                 // wave-uniform branch
                    const float* rowp = dp + hcl[hh];
                    float4 xv[6];
                    #pragma unroll
                    for (int p = 0; p < 6; ++p)
                        xv[p] = *(const float4*)(rowp + wcl[p]);
                    xv[0].x *= mwL; xv[0].y *= mwL; xv[0].z *= mwL; xv[0].w *= mwL;
                    xv[5].x *= mwR; xv[5].y *= mwR; xv[5].z *= mwR; xv[5].w *= mwR;
                    #pragma unroll
                    for (int m = 0; m < 6; ++m) {
                        if (m >= k - 2 && m <= k) {      // folds at compile time
                            const int wz  = k - m;       // weight z-tap
                            const int aid = m % 3;
                            #pragma unroll
                            for (int ww = 0; ww < 3; ++ww) {
                                const float4 wvv = *(const float4*)(&wS[((wz * 3 + hh) * 3 + ww) * 64 + c0]);
                                #pragma unroll
                                for (int r = 0; r < 4; ++r) {
                                    acc[aid][r].x += xv[r + ww].x * wvv.x;
                                    acc[aid][r].y += xv[r + ww].y * wvv.y;
                                    acc[aid][r].z += xv[r + ww].z * wvv.z;
                                    acc[aid][r].w += xv[r + ww].w * wvv.w;
                                }
                            }
                        }
                    }
                }
            }
        }

        // ---- finish output m = k-2 ----
        if (k >= 2) {
            const int m   = k - 2;
            const int aid = m % 3;

            __syncthreads();   // prev GEMM's yS reads complete (WAR)

            // BN1 + ReLU + bf16 -> yS
            {
                float4 s1 = *(const float4*)(&sS[c0]);
                float4 t1 = *(const float4*)(&tS[c0]);
                #pragma unroll
                for (int r = 0; r < 4; ++r) {
                    ushort4 o;
                    o.x = f2bf(fmaxf(acc[aid][r].x * s1.x + t1.x, 0.f));
                    o.y = f2bf(fmaxf(acc[aid][r].y * s1.y + t1.y, 0.f));
                    o.z = f2bf(fmaxf(acc[aid][r].z * s1.z + t1.z, 0.f));
                    o.w = f2bf(fmaxf(acc[aid][r].w * s1.w + t1.w, 0.f));
                    *(ushort4*)(&yS[(ty * 4 + r) * 72 + c0]) = o;
                    acc[aid][r] = make_float4(0.f, 0.f, 0.f, 0.f);  // recycle
                }
            }
            __syncthreads();   // yS visible (RAW)

            // GEMM: 4 waves, wave = 16 rows x 128 cols, K=64, 2 MFMA k-steps
            const short8 a0 = *(const short8*)(&yS[(wv * 16 + lrow) * 72 + quad * 8]);
            const short8 a1 = *(const short8*)(&yS[(wv * 16 + lrow) * 72 + 32 + quad * 8]);

            v4f gacc[8];
            #pragma unroll
            for (int nn = 0; nn < 8; ++nn) gacc[nn] = (v4f){0.f, 0.f, 0.f, 0.f};

            #pragma unroll
            for (int nn = 0; nn < 8; ++nn) {
                short8 b0 = *(const short8*)(Wt + ((nn * 2 + 0) * 64 + lane) * 8);
                short8 b1 = *(const short8*)(Wt + ((nn * 2 + 1) * 64 + lane) * 8);
                gacc[nn] = __builtin_amdgcn_mfma_f32_16x16x32_bf16(a0, b0, gacc[nn], 0, 0, 0);
                gacc[nn] = __builtin_amdgcn_mfma_f32_16x16x32_bf16(a1, b1, gacc[nn], 0, 0, 0);
            }

            // BN2 + ReLU epilogue. D: col=lane&15, row=quad*4+reg.
            int d = d0 + m;
            long base_out = ((((long)b * 48 + d) * 48 + (h0 + wv)) * 48 + w0) * 128;
            #pragma unroll
            for (int nn = 0; nn < 8; ++nn) {
                int f = nn * 16 + lrow;
                float sf = s2S[f];
                float tf = t2S[f];
                #pragma unroll
                for (int r = 0; r < 4; ++r) {
                    float v = fmaxf(gacc[nn][r] * sf + tf, 0.f);
                    out[base_out + (quad * 4 + r) * 128 + f] = v;
                }
            }
        }
    }
}

// ---------------------------------------------------------------------------
extern "C" void kernel_launch(void* const* d_in, const int* in_sizes, int n_in,
                              void* d_out, int out_size, void* d_ws, size_t ws_size,
                              hipStream_t stream)
{
    const float* x   = (const float*)d_in[0];
    const float* dwk = (const float*)d_in[1];
    const float* dwb = (const float*)d_in[2];
    const float* g1  = (const float*)d_in[3];
    const float* b1  = (const float*)d_in[4];
    const float* m1  = (const float*)d_in[5];
    const float* v1  = (const float*)d_in[6];
    const float* pw  = (const float*)d_in[7];
    const float* pwb = (const float*)d_in[8];
    const float* g2  = (const float*)d_in[9];
    const float* b2  = (const float*)d_in[10];
    const float* m2  = (const float*)d_in[11];
    const float* v2  = (const float*)d_in[12];

    float* outp = (float*)d_out;

    float* scale1 = (float*)d_ws;
    float* shift1 = scale1 + 64;
    float* s2     = scale1 + 128;
    float* t2     = scale1 + 256;
    unsigned short* Wt = (unsigned short*)((char*)d_ws + 2048);

    hipLaunchKernelGGL(prep_kernel, dim3(32), dim3(256), 0, stream,
                       dwb, g1, b1, m1, v1, pw, pwb, g2, b2, m2, v2,
                       scale1, shift1, s2, t2, Wt);

    hipLaunchKernelGGL(fused_kernel, dim3(576), dim3(256), 0, stream,
                       x, dwk, scale1, shift1, Wt, s2, t2, outp);
}